// Round 7
// baseline (210.631 us; speedup 1.0000x reference)
//
#include <hip/hip_runtime.h>

#define BATCH 4
#define SEQ   4096
#define DIM   1024
#define NCH   512
#define CHK   8
#define NROWS (BATCH*SEQ)
#define NKT   32            // gemm K-tiles (1024/32)

typedef __attribute__((ext_vector_type(4))) float f32x4;
typedef __attribute__((ext_vector_type(8))) short shortx8;
typedef __attribute__((ext_vector_type(4))) short shortx4;

static __device__ __forceinline__ unsigned short f2bf(float f){
    unsigned int u = __float_as_uint(f);
    u += 0x7FFFu + ((u >> 16) & 1u);
    return (unsigned short)(u >> 16);
}
static __device__ __forceinline__ float bf2f(unsigned short h){
    return __uint_as_float(((unsigned int)h) << 16);
}
static __device__ __forceinline__ float sigmoidf_fast(float x){
    return 1.0f / (1.0f + __expf(-x));
}
static __device__ __forceinline__ shortx4 pack4(f32x4 s){
    shortx4 o;
    o.x = (short)f2bf(s.x); o.y = (short)f2bf(s.y);
    o.z = (short)f2bf(s.z); o.w = (short)f2bf(s.w);
    return o;
}
static __device__ __forceinline__ f32x4 unpack4(shortx4 s){
    f32x4 o;
    o.x = bf2f((unsigned short)s.x); o.y = bf2f((unsigned short)s.y);
    o.z = bf2f((unsigned short)s.z); o.w = bf2f((unsigned short)s.w);
    return o;
}

// ---------------- K1: shift + decay + exp + chunk-local scan (+ fused W-pack) ----
__global__ __launch_bounds__(256) void k_shift_scan(
    const float* __restrict__ X, const float* __restrict__ XP,
    const float* __restrict__ mu_p, const float* __restrict__ dw,
    const float* __restrict__ db_p,
    const float* __restrict__ Wr, const float* __restrict__ Wv,
    unsigned short* __restrict__ Wcat,
    unsigned short* __restrict__ shifted,
    unsigned short* __restrict__ b_local, float* __restrict__ a_local,
    float* __restrict__ cumP)
{
    const int tid  = threadIdx.x;

    if (blockIdx.x >= 512){            // ---- weight pack path ----
        const int pb = blockIdx.x - 512;       // 0..63
        #pragma unroll 4
        for (int i = 0; i < 32; ++i){
            const int n = pb*32 + i;
            const int grp = n >> 5, r = n & 31;
            const float* src = (r < 16) ? (Wr + (size_t)(grp*16 + r)*DIM)
                                        : (Wv + (size_t)(grp*16 + (r-16))*DIM);
            f32x4 v = reinterpret_cast<const f32x4*>(src)[tid];
            reinterpret_cast<shortx4*>(Wcat)[n*256 + tid] = pack4(v);
        }
        return;
    }

    const int lane = tid & 63;
    const int wid  = tid >> 6;
    const int cid  = blockIdx.x*4 + wid;
    const int batch = cid >> 9;
    const int chunk = cid & (NCH-1);
    const int row0  = batch*SEQ + chunk*CHK;

    const float mu = mu_p[0];
    const float om = 1.0f - mu;
    const float db = db_p[0];

    const f32x4* dwv = reinterpret_cast<const f32x4*>(dw);
    const f32x4 w0 = dwv[lane], w1 = dwv[64+lane], w2 = dwv[128+lane], w3 = dwv[192+lane];

    f32x4 b0 = {0,0,0,0}, b1 = {0,0,0,0}, b2 = {0,0,0,0}, b3 = {0,0,0,0};
    float a_run = 0.f, cp = 1.f;

    const f32x4* Xv  = reinterpret_cast<const f32x4*>(X);
    const f32x4* XPv = reinterpret_cast<const f32x4*>(XP);
    shortx4* BL = reinterpret_cast<shortx4*>(b_local);
    shortx4* SH = reinterpret_cast<shortx4*>(shifted);

    for (int r = 0; r < CHK; ++r){
        const int row = row0 + r;
        const int rb  = row*(DIM/4);

        f32x4 x0 = Xv[rb+lane],     x1 = Xv[rb+64+lane],
              x2 = Xv[rb+128+lane], x3 = Xv[rb+192+lane];
        f32x4 p0 = XPv[rb+lane],     p1 = XPv[rb+64+lane],
              p2 = XPv[rb+128+lane], p3 = XPv[rb+192+lane];
        f32x4 s0 = mu*x0 + om*p0, s1 = mu*x1 + om*p1;
        f32x4 s2 = mu*x2 + om*p2, s3 = mu*x3 + om*p3;

        SH[rb+lane]     = pack4(s0);
        SH[rb+64+lane]  = pack4(s1);
        SH[rb+128+lane] = pack4(s2);
        SH[rb+192+lane] = pack4(s3);

        float dot = s0.x*w0.x + s0.y*w0.y + s0.z*w0.z + s0.w*w0.w
                  + s1.x*w1.x + s1.y*w1.y + s1.z*w1.z + s1.w*w1.w
                  + s2.x*w2.x + s2.y*w2.y + s2.z*w2.z + s2.w*w2.w
                  + s3.x*w3.x + s3.y*w3.y + s3.z*w3.z + s3.w*w3.w;

        f32x4 e0, e1, e2, e3;
        e0.x=__expf(s0.x); e0.y=__expf(s0.y); e0.z=__expf(s0.z); e0.w=__expf(s0.w);
        e1.x=__expf(s1.x); e1.y=__expf(s1.y); e1.z=__expf(s1.z); e1.w=__expf(s1.w);
        e2.x=__expf(s2.x); e2.y=__expf(s2.y); e2.z=__expf(s2.z); e2.w=__expf(s2.w);
        e3.x=__expf(s3.x); e3.y=__expf(s3.y); e3.z=__expf(s3.z); e3.w=__expf(s3.w);
        float ea = e0.x+e0.y+e0.z+e0.w + e1.x+e1.y+e1.z+e1.w
                 + e2.x+e2.y+e2.z+e2.w + e3.x+e3.y+e3.z+e3.w;

        #pragma unroll
        for (int off = 1; off < 64; off <<= 1){
            dot += __shfl_xor(dot, off, 64);
            ea  += __shfl_xor(ea,  off, 64);
        }

        const float dt = sigmoidf_fast(dot + db);
        a_run = dt*a_run + ea;
        cp   *= dt;
        b0 = dt*b0 + e0*s0;  b1 = dt*b1 + e1*s1;
        b2 = dt*b2 + e2*s2;  b3 = dt*b3 + e3*s3;

        BL[rb+lane]     = pack4(b0);
        BL[rb+64+lane]  = pack4(b1);
        BL[rb+128+lane] = pack4(b2);
        BL[rb+192+lane] = pack4(b3);
        if (lane == 0){ a_local[row] = a_run; cumP[row] = cp; }
    }
}

// ---------------- K2: sequential carry combine (depth-16 vector prefetch) ----
__global__ __launch_bounds__(64) void k_combine(
    const unsigned short* __restrict__ b_local, const float* __restrict__ a_local,
    const float* __restrict__ cumP,
    float* __restrict__ carryA, unsigned short* __restrict__ carryB)
{
    const int batch = blockIdx.x >> 2;
    const int dseg  = blockIdx.x & 3;
    const int tid = threadIdx.x;
    const int d0 = dseg*256 + tid*4;

    __shared__ float sP[NCH], sA[NCH];
    for (int c = tid; c < NCH; c += 64){
        const int er = batch*SEQ + c*CHK + (CHK-1);
        sP[c] = cumP[er];
        sA[c] = a_local[er];
    }
    __syncthreads();

    const unsigned short* bl = b_local + (size_t)batch*SEQ*DIM + d0;
    unsigned short* cB = carryB + (size_t)batch*NCH*DIM + d0;
    const bool wA = (dseg == 0 && tid == 0);
    float* cAp = carryA + batch*NCH;

    shortx4 pf[16];
    #pragma unroll
    for (int i = 0; i < 16; ++i)
        pf[i] = *reinterpret_cast<const shortx4*>(bl + (i*CHK + CHK-1)*DIM);

    f32x4 cb = {0,0,0,0};
    float ca = 0.f;

    for (int cc = 0; cc < NCH; cc += 16){
        const bool more = (cc + 16 < NCH);
        #pragma unroll
        for (int k = 0; k < 16; ++k){
            const int c = cc + k;
            f32x4 v = unpack4(pf[k]);
            if (more)
                pf[k] = *reinterpret_cast<const shortx4*>(bl + ((c+16)*CHK + CHK-1)*DIM);
            *reinterpret_cast<shortx4*>(cB + (size_t)c*DIM) = pack4(cb);
            if (wA) cAp[c] = ca;
            const float p = sP[c];
            cb = p*cb + v;
            ca = p*ca + sA[c];
        }
    }
}

// ---------------- K3: carry fixup + divide + LN1 -> merged (wave-per-row) ----
__global__ __launch_bounds__(256) void k_fix_ln1(
    const unsigned short* __restrict__ b_local, const float* __restrict__ a_local,
    const float* __restrict__ cumP, const float* __restrict__ carryA,
    const unsigned short* __restrict__ carryB,
    const float* __restrict__ g1, const float* __restrict__ bb1,
    unsigned short* __restrict__ merged)
{
    const int tid = threadIdx.x, lane = tid & 63, wid = tid >> 6;
    const int row = blockIdx.x*4 + wid;
    const int batch = row >> 12;
    const int c = (row & (SEQ-1)) >> 3;

    const float cpv = cumP[row];
    const float a = a_local[row] + cpv * carryA[batch*NCH + c];
    const float inv_a = 1.0f / (a + 1e-8f);

    const shortx4* BL = reinterpret_cast<const shortx4*>(b_local) + (size_t)row*256;
    const shortx4* CB = reinterpret_cast<const shortx4*>(carryB) + (size_t)(batch*NCH + c)*256;

    f32x4 o[4];
    float s = 0.f, s2 = 0.f;
    #pragma unroll
    for (int j = 0; j < 4; ++j){
        f32x4 bl = unpack4(BL[j*64 + lane]);
        f32x4 cb = unpack4(CB[j*64 + lane]);
        f32x4 v = (bl + cpv*cb) * inv_a;
        o[j] = v;
        s  += v.x+v.y+v.z+v.w;
        s2 += v.x*v.x + v.y*v.y + v.z*v.z + v.w*v.w;
    }
    #pragma unroll
    for (int off = 1; off < 64; off <<= 1){
        s  += __shfl_xor(s,  off, 64);
        s2 += __shfl_xor(s2, off, 64);
    }
    const float mean = s * (1.0f/DIM);
    const float rstd = rsqrtf(s2*(1.0f/DIM) - mean*mean + 1e-5f);
    shortx4* MG = reinterpret_cast<shortx4*>(merged) + (size_t)row*256;
    #pragma unroll
    for (int j = 0; j < 4; ++j){
        f32x4 gg = reinterpret_cast<const f32x4*>(g1)[j*64 + lane];
        f32x4 bb = reinterpret_cast<const f32x4*>(bb1)[j*64 + lane];
        MG[j*64 + lane] = pack4((o[j] - mean)*rstd*gg + bb);
    }
}

// ---------------- K5: 256x256 bf16 GEMM, cross-tile register pipeline ----------
// BK=32, 32 K-tiles, 8 waves (2m x 4n), per-wave C 128x64 (acc[8][4]).
// Two fragment sets (afA/bfA, afB/bfB): ds_reads for tile T+1 are issued
// BEFORE the 32-MFMA cluster of tile T -> LDS service (1152 cyc/CU) hides
// under MFMA (1241 cyc/CU). Two raw barriers/tile:
//   lgkm(0); BAR-A            (all waves' reads of buf[T&1] executed)
//   STAGE(T+2)->buf[T&1]      (strict WAR: write issued after BAR-A)
//   vmcnt(4)                  (own STAGE(T+1) loads confirmed)
//   BAR-B                     (ALL waves' STAGE(T+1) confirmed)
//   LOADF(T+1) <- buf[(T+1)&1]
//   MFMA x32 on tile-T fragments
// Subtiles 16x32 bf16 (1KB), col-group XOR swizzle (cg^=2 @ row&8) on both
// staging source and ds_read (validated rounds 3-6).
typedef __attribute__((address_space(3))) unsigned int lds_uint;
typedef __attribute__((address_space(1))) unsigned int glob_uint;
static __device__ __forceinline__ void gload16(const unsigned short* g, char* l){
    __builtin_amdgcn_global_load_lds((const glob_uint*)g, (lds_uint*)l, 16, 0, 0);
}
#define SBAR() do { __builtin_amdgcn_sched_barrier(0); __builtin_amdgcn_s_barrier(); __builtin_amdgcn_sched_barrier(0); } while(0)
#define LGKM0() do { asm volatile("s_waitcnt lgkmcnt(0)" ::: "memory"); __builtin_amdgcn_sched_barrier(0); } while(0)
#define VMC(n)  asm volatile("s_waitcnt vmcnt(" #n ")" ::: "memory")
#define LDSE 136

__global__ __launch_bounds__(512, 2) void k_gemm(
    const unsigned short* __restrict__ A,    // merged bf16 [16384][1024]
    const unsigned short* __restrict__ Bt,   // Wcat  bf16 [2048][1024]
    const float* __restrict__ rbias, const float* __restrict__ vbias,
    unsigned short* __restrict__ gv)         // bf16 [16384][1024]
{
    __shared__ __align__(16) char lds[69632];   // 2 x 32KB bufs; epilogue 69632
    const int tid  = threadIdx.x;
    const int lane = tid & 63;
    const int wid  = tid >> 6;
    const int wm   = wid >> 2;       // 0..1
    const int wn   = wid & 3;        // 0..3

    const int bid  = blockIdx.x;
    const int wgid = (bid & 7)*64 + (bid >> 3);
    const int mt = wgid >> 3, nt = wgid & 7;
    const int m0 = mt*256, n0 = nt*256;

    // staging source (pre-swizzled col-group)
    const int rin = lane >> 2;
    const int scg = (lane & 3) ^ (((lane >> 5) & 1) << 1);
    const unsigned short* gA = A  + (size_t)(m0 + wid*32 + rin)*DIM + scg*8;
    const unsigned short* gB = Bt + (size_t)(n0 + wid*32 + rin)*DIM + scg*8;

    // fragment read offset (matching swizzle)
    const int fr = lane & 15, fq = lane >> 4;
    const int soff = fr*64 + ((fq*16) ^ ((fr & 8) ? 32 : 0));

    f32x4 acc[8][4];
    #pragma unroll
    for (int i = 0; i < 8; ++i)
        #pragma unroll
        for (int j = 0; j < 4; ++j) acc[i][j] = (f32x4){0,0,0,0};

    auto STAGE = [&](int tk){          // 4 gloads: A 2 subtiles + B 2 subtiles
        char* da = lds + (tk & 1)*32768 + wid*2048;
        const unsigned short* sa = gA + tk*32;
        gload16(sa,          da);
        gload16(sa + 16*DIM, da + 1024);
        char* db = lds + (tk & 1)*32768 + 16384 + wid*2048;
        const unsigned short* sb = gB + tk*32;
        gload16(sb,          db);
        gload16(sb + 16*DIM, db + 1024);
    };

    shortx8 afA[8], bfA[4], afB[8], bfB[4];

    #define LOADF(AF, BF, bb) do {                                              \
        _Pragma("unroll")                                                       \
        for (int mf = 0; mf < 8; ++mf)                                          \
            AF[mf] = *reinterpret_cast<const shortx8*>((bb) + (wm*8 + mf)*1024 + soff); \
        _Pragma("unroll")                                                       \
        for (int nf = 0; nf < 4; ++nf)                                          \
            BF[nf] = *reinterpret_cast<const shortx8*>((bb) + 16384 + (wn*4 + nf)*1024 + soff); \
    } while (0)

    #define MFMA32(AF, BF) do {                                                 \
        __builtin_amdgcn_s_setprio(1);                                          \
        _Pragma("unroll")                                                       \
        for (int mf = 0; mf < 8; ++mf)                                          \
            _Pragma("unroll")                                                   \
            for (int nf = 0; nf < 4; ++nf)                                      \
                acc[mf][nf] = __builtin_amdgcn_mfma_f32_16x16x32_bf16(          \
                    AF[mf], BF[nf], acc[mf][nf], 0, 0, 0);                      \
        __builtin_amdgcn_s_setprio(0);                                          \
    } while (0)

    #define BODY(T, AFc, BFc, AFn, BFn) do {                                    \
        LGKM0();                                                                \
        SBAR();                       /* BAR-A: reads of buf[T&1] executed */   \
        if ((T) + 2 < NKT){ STAGE((T) + 2); VMC(4); }                           \
        else if ((T) + 2 == NKT){ VMC(0); }                                     \
        SBAR();                       /* BAR-B: STAGE(T+1) confirmed       */   \
        if ((T) + 1 < NKT){ LOADF(AFn, BFn, lds + (((T) + 1) & 1)*32768); }     \
        __builtin_amdgcn_sched_barrier(0);                                      \
        MFMA32(AFc, BFc);                                                       \
    } while (0)

    // prologue: tiles 0,1 staged; tile 0 confirmed; tile-0 fragments issued
    STAGE(0); STAGE(1);
    VMC(4);
    SBAR();
    LOADF(afA, bfA, lds);

    for (int T = 0; T < NKT; T += 2){
        BODY(T,     afA, bfA, afB, bfB);
        BODY(T + 1, afB, bfB, afA, bfA);
    }

    // ---- epilogue: sigmoid(gate)*value -> padded LDS transpose -> store ----
    __syncthreads();
    unsigned short* ep = reinterpret_cast<unsigned short*>(lds);  // [256][LDSE]
    #pragma unroll
    for (int pr = 0; pr < 2; ++pr){
        const int el = wn*32 + pr*16 + fr;
        const float rbe = rbias[nt*128 + el];
        const float vbe = vbias[nt*128 + el];
        #pragma unroll
        for (int mf = 0; mf < 8; ++mf){
            const int rbase = wm*128 + mf*16 + fq*4;
            f32x4 ga = acc[mf][2*pr], va = acc[mf][2*pr+1];
            #pragma unroll
            for (int q = 0; q < 4; ++q){
                const float g = sigmoidf_fast(ga[q] + rbe);
                ep[(rbase + q)*LDSE + el] = f2bf(g*(va[q] + vbe));
            }
        }
    }
    __syncthreads();
    #pragma unroll
    for (int p = 0; p < 8; ++p){
        const int r  = p*32 + (tid >> 4);
        const int c8 = tid & 15;
        shortx8 val = *reinterpret_cast<const shortx8*>(&ep[r*LDSE + c8*8]);
        *reinterpret_cast<shortx8*>(&gv[(size_t)(m0 + r)*DIM + nt*128 + c8*8]) = val;
    }
    #undef BODY
    #undef MFMA32
    #undef LOADF
}

// ---------------- K6: LN2 + residual (wave-per-row) ----------------
__global__ __launch_bounds__(256) void k_ln2_res(
    const unsigned short* __restrict__ gvb, const unsigned short* __restrict__ shifted,
    const float* __restrict__ g2, const float* __restrict__ b2,
    float* __restrict__ out)
{
    const int tid = threadIdx.x, lane = tid & 63, wid = tid >> 6;
    const int row = blockIdx.x*4 + wid;

    const shortx4* GV = reinterpret_cast<const shortx4*>(gvb) + (size_t)row*256;
    const shortx4* SH = reinterpret_cast<const shortx4*>(shifted) + (size_t)row*256;

    f32x4 v[4];
    float s = 0.f, s2 = 0.f;
    #pragma unroll
    for (int j = 0; j < 4; ++j){
        f32x4 x = unpack4(GV[j*64 + lane]);
        v[j] = x;
        s  += x.x+x.y+x.z+x.w;
        s2 += x.x*x.x + x.y*x.y + x.z*x.z + x.w*x.w;
    }
    #pragma unroll
    for (int off = 1; off < 64; off <<= 1){
        s  += __shfl_xor(s,  off, 64);
        s2 += __shfl_xor(s2, off, 64);
    }
    const float mean = s * (1.0f/DIM);
    const float rstd = rsqrtf(s2*(1.0f/DIM) - mean*mean + 1e-5f);
    f32x4* O = reinterpret_cast<f32x4*>(out) + (size_t)row*256;
    #pragma unroll
    for (int j = 0; j < 4; ++j){
        f32x4 gg = reinterpret_cast<const f32x4*>(g2)[j*64 + lane];
        f32x4 bb = reinterpret_cast<const f32x4*>(b2)[j*64 + lane];
        f32x4 sh = unpack4(SH[j*64 + lane]);
        O[j*64 + lane] = sh + (v[j] - mean)*rstd*gg + bb;
    }
}

extern "C" void kernel_launch(void* const* d_in, const int* in_sizes, int n_in,
                              void* d_out, int out_size, void* d_ws, size_t ws_size,
                              hipStream_t stream)
{
    (void)in_sizes; (void)n_in; (void)out_size; (void)ws_size;
    const float* x     = (const float*)d_in[0];
    const float* xprev = (const float*)d_in[1];
    const float* mu    = (const float*)d_in[2];
    const float* dw    = (const float*)d_in[3];
    const float* db    = (const float*)d_in[4];
    const float* ln1g  = (const float*)d_in[5];
    const float* ln1b  = (const float*)d_in[6];
    const float* Wr    = (const float*)d_in[7];
    const float* Wrb   = (const float*)d_in[8];
    const float* Wv    = (const float*)d_in[9];
    const float* Wvb   = (const float*)d_in[10];
    const float* ln2g  = (const float*)d_in[11];
    const float* ln2b  = (const float*)d_in[12];
    float* out = (float*)d_out;

    char* ws = (char*)d_ws;
    size_t off = 0;
    auto alloc = [&](size_t bytes) -> void* {
        void* p = ws + off;
        off += (bytes + 255) & ~(size_t)255;
        return p;
    };
    unsigned short* shifted = (unsigned short*)alloc((size_t)NROWS*DIM*2);
    unsigned short* b_local = (unsigned short*)alloc((size_t)NROWS*DIM*2);
    unsigned short* merged  = (unsigned short*)alloc((size_t)NROWS*DIM*2);
    unsigned short* carryB  = (unsigned short*)alloc((size_t)BATCH*NCH*DIM*2);
    unsigned short* Wcat    = (unsigned short*)alloc((size_t)2048*1024*2);
    float* a_local          = (float*)alloc((size_t)NROWS*4);
    float* cumP             = (float*)alloc((size_t)NROWS*4);
    float* carryA           = (float*)alloc((size_t)BATCH*NCH*4);
    unsigned short* gvbuf   = b_local;   // b_local dead after k_fix_ln1

    hipLaunchKernelGGL(k_shift_scan, dim3(576),  dim3(256), 0, stream,
                       x, xprev, mu, dw, db, Wr, Wv, Wcat, shifted, b_local, a_local, cumP);
    hipLaunchKernelGGL(k_combine,    dim3(16),   dim3(64),  0, stream,
                       b_local, a_local, cumP, carryA, carryB);
    hipLaunchKernelGGL(k_fix_ln1,    dim3(4096), dim3(256), 0, stream,
                       b_local, a_local, cumP, carryA, carryB, ln1g, ln1b, merged);
    hipLaunchKernelGGL(k_gemm,       dim3(512),  dim3(512), 0, stream,
                       merged, Wcat, Wrb, Wvb, gvbuf);
    hipLaunchKernelGGL(k_ln2_res,    dim3(4096), dim3(256), 0, stream,
                       gvbuf, shifted, ln2g, ln2b, out);
}

// Round 8
// 208.106 us; speedup vs baseline: 1.0121x; 1.0121x over previous
//
#include <hip/hip_runtime.h>

#define BATCH 4
#define SEQ   4096
#define DIM   1024
#define NCH   512
#define CHK   8
#define NROWS (BATCH*SEQ)
#define NTG   16            // gemm K-tiles (1024/64)
#define NPAIR 8             // pairs of K-tiles

typedef __attribute__((ext_vector_type(4))) float f32x4;
typedef __attribute__((ext_vector_type(8))) short shortx8;
typedef __attribute__((ext_vector_type(4))) short shortx4;

static __device__ __forceinline__ unsigned short f2bf(float f){
    unsigned int u = __float_as_uint(f);
    u += 0x7FFFu + ((u >> 16) & 1u);
    return (unsigned short)(u >> 16);
}
static __device__ __forceinline__ float bf2f(unsigned short h){
    return __uint_as_float(((unsigned int)h) << 16);
}
static __device__ __forceinline__ float sigmoidf_fast(float x){
    return 1.0f / (1.0f + __expf(-x));
}
static __device__ __forceinline__ shortx4 pack4(f32x4 s){
    shortx4 o;
    o.x = (short)f2bf(s.x); o.y = (short)f2bf(s.y);
    o.z = (short)f2bf(s.z); o.w = (short)f2bf(s.w);
    return o;
}
static __device__ __forceinline__ f32x4 unpack4(shortx4 s){
    f32x4 o;
    o.x = bf2f((unsigned short)s.x); o.y = bf2f((unsigned short)s.y);
    o.z = bf2f((unsigned short)s.z); o.w = bf2f((unsigned short)s.w);
    return o;
}

// ---------------- K1: shift + decay + exp + chunk-local scan (+ fused W-pack) ----
__global__ __launch_bounds__(256) void k_shift_scan(
    const float* __restrict__ X, const float* __restrict__ XP,
    const float* __restrict__ mu_p, const float* __restrict__ dw,
    const float* __restrict__ db_p,
    const float* __restrict__ Wr, const float* __restrict__ Wv,
    unsigned short* __restrict__ Wcat,
    unsigned short* __restrict__ shifted,
    unsigned short* __restrict__ b_local, float* __restrict__ a_local,
    float* __restrict__ cumP)
{
    const int tid  = threadIdx.x;

    if (blockIdx.x >= 512){            // ---- weight pack path ----
        const int pb = blockIdx.x - 512;       // 0..63
        #pragma unroll 4
        for (int i = 0; i < 32; ++i){
            const int n = pb*32 + i;
            const int grp = n >> 5, r = n & 31;
            const float* src = (r < 16) ? (Wr + (size_t)(grp*16 + r)*DIM)
                                        : (Wv + (size_t)(grp*16 + (r-16))*DIM);
            f32x4 v = reinterpret_cast<const f32x4*>(src)[tid];
            reinterpret_cast<shortx4*>(Wcat)[n*256 + tid] = pack4(v);
        }
        return;
    }

    const int lane = tid & 63;
    const int wid  = tid >> 6;
    const int cid  = blockIdx.x*4 + wid;
    const int batch = cid >> 9;
    const int chunk = cid & (NCH-1);
    const int row0  = batch*SEQ + chunk*CHK;

    const float mu = mu_p[0];
    const float om = 1.0f - mu;
    const float db = db_p[0];

    const f32x4* dwv = reinterpret_cast<const f32x4*>(dw);
    const f32x4 w0 = dwv[lane], w1 = dwv[64+lane], w2 = dwv[128+lane], w3 = dwv[192+lane];

    f32x4 b0 = {0,0,0,0}, b1 = {0,0,0,0}, b2 = {0,0,0,0}, b3 = {0,0,0,0};
    float a_run = 0.f, cp = 1.f;

    const f32x4* Xv  = reinterpret_cast<const f32x4*>(X);
    const f32x4* XPv = reinterpret_cast<const f32x4*>(XP);
    shortx4* BL = reinterpret_cast<shortx4*>(b_local);
    shortx4* SH = reinterpret_cast<shortx4*>(shifted);

    for (int r = 0; r < CHK; ++r){
        const int row = row0 + r;
        const int rb  = row*(DIM/4);

        f32x4 x0 = Xv[rb+lane],     x1 = Xv[rb+64+lane],
              x2 = Xv[rb+128+lane], x3 = Xv[rb+192+lane];
        f32x4 p0 = XPv[rb+lane],     p1 = XPv[rb+64+lane],
              p2 = XPv[rb+128+lane], p3 = XPv[rb+192+lane];
        f32x4 s0 = mu*x0 + om*p0, s1 = mu*x1 + om*p1;
        f32x4 s2 = mu*x2 + om*p2, s3 = mu*x3 + om*p3;

        SH[rb+lane]     = pack4(s0);
        SH[rb+64+lane]  = pack4(s1);
        SH[rb+128+lane] = pack4(s2);
        SH[rb+192+lane] = pack4(s3);

        float dot = s0.x*w0.x + s0.y*w0.y + s0.z*w0.z + s0.w*w0.w
                  + s1.x*w1.x + s1.y*w1.y + s1.z*w1.z + s1.w*w1.w
                  + s2.x*w2.x + s2.y*w2.y + s2.z*w2.z + s2.w*w2.w
                  + s3.x*w3.x + s3.y*w3.y + s3.z*w3.z + s3.w*w3.w;

        f32x4 e0, e1, e2, e3;
        e0.x=__expf(s0.x); e0.y=__expf(s0.y); e0.z=__expf(s0.z); e0.w=__expf(s0.w);
        e1.x=__expf(s1.x); e1.y=__expf(s1.y); e1.z=__expf(s1.z); e1.w=__expf(s1.w);
        e2.x=__expf(s2.x); e2.y=__expf(s2.y); e2.z=__expf(s2.z); e2.w=__expf(s2.w);
        e3.x=__expf(s3.x); e3.y=__expf(s3.y); e3.z=__expf(s3.z); e3.w=__expf(s3.w);
        float ea = e0.x+e0.y+e0.z+e0.w + e1.x+e1.y+e1.z+e1.w
                 + e2.x+e2.y+e2.z+e2.w + e3.x+e3.y+e3.z+e3.w;

        #pragma unroll
        for (int off = 1; off < 64; off <<= 1){
            dot += __shfl_xor(dot, off, 64);
            ea  += __shfl_xor(ea,  off, 64);
        }

        const float dt = sigmoidf_fast(dot + db);
        a_run = dt*a_run + ea;
        cp   *= dt;
        b0 = dt*b0 + e0*s0;  b1 = dt*b1 + e1*s1;
        b2 = dt*b2 + e2*s2;  b3 = dt*b3 + e3*s3;

        BL[rb+lane]     = pack4(b0);
        BL[rb+64+lane]  = pack4(b1);
        BL[rb+128+lane] = pack4(b2);
        BL[rb+192+lane] = pack4(b3);
        if (lane == 0){ a_local[row] = a_run; cumP[row] = cp; }
    }
}

// ---------------- K2: sequential carry combine (depth-16 vector prefetch) ----
__global__ __launch_bounds__(64) void k_combine(
    const unsigned short* __restrict__ b_local, const float* __restrict__ a_local,
    const float* __restrict__ cumP,
    float* __restrict__ carryA, unsigned short* __restrict__ carryB)
{
    const int batch = blockIdx.x >> 2;
    const int dseg  = blockIdx.x & 3;
    const int tid = threadIdx.x;
    const int d0 = dseg*256 + tid*4;

    __shared__ float sP[NCH], sA[NCH];
    for (int c = tid; c < NCH; c += 64){
        const int er = batch*SEQ + c*CHK + (CHK-1);
        sP[c] = cumP[er];
        sA[c] = a_local[er];
    }
    __syncthreads();

    const unsigned short* bl = b_local + (size_t)batch*SEQ*DIM + d0;
    unsigned short* cB = carryB + (size_t)batch*NCH*DIM + d0;
    const bool wA = (dseg == 0 && tid == 0);
    float* cAp = carryA + batch*NCH;

    shortx4 pf[16];
    #pragma unroll
    for (int i = 0; i < 16; ++i)
        pf[i] = *reinterpret_cast<const shortx4*>(bl + (i*CHK + CHK-1)*DIM);

    f32x4 cb = {0,0,0,0};
    float ca = 0.f;

    for (int cc = 0; cc < NCH; cc += 16){
        const bool more = (cc + 16 < NCH);
        #pragma unroll
        for (int k = 0; k < 16; ++k){
            const int c = cc + k;
            f32x4 v = unpack4(pf[k]);
            if (more)
                pf[k] = *reinterpret_cast<const shortx4*>(bl + ((c+16)*CHK + CHK-1)*DIM);
            *reinterpret_cast<shortx4*>(cB + (size_t)c*DIM) = pack4(cb);
            if (wA) cAp[c] = ca;
            const float p = sP[c];
            cb = p*cb + v;
            ca = p*ca + sA[c];
        }
    }
}

// ---------------- K3: carry fixup + divide + LN1 -> merged (wave-per-row) ----
__global__ __launch_bounds__(256) void k_fix_ln1(
    const unsigned short* __restrict__ b_local, const float* __restrict__ a_local,
    const float* __restrict__ cumP, const float* __restrict__ carryA,
    const unsigned short* __restrict__ carryB,
    const float* __restrict__ g1, const float* __restrict__ bb1,
    unsigned short* __restrict__ merged)
{
    const int tid = threadIdx.x, lane = tid & 63, wid = tid >> 6;
    const int row = blockIdx.x*4 + wid;
    const int batch = row >> 12;
    const int c = (row & (SEQ-1)) >> 3;

    const float cpv = cumP[row];
    const float a = a_local[row] + cpv * carryA[batch*NCH + c];
    const float inv_a = 1.0f / (a + 1e-8f);

    const shortx4* BL = reinterpret_cast<const shortx4*>(b_local) + (size_t)row*256;
    const shortx4* CB = reinterpret_cast<const shortx4*>(carryB) + (size_t)(batch*NCH + c)*256;

    f32x4 o[4];
    float s = 0.f, s2 = 0.f;
    #pragma unroll
    for (int j = 0; j < 4; ++j){
        f32x4 bl = unpack4(BL[j*64 + lane]);
        f32x4 cb = unpack4(CB[j*64 + lane]);
        f32x4 v = (bl + cpv*cb) * inv_a;
        o[j] = v;
        s  += v.x+v.y+v.z+v.w;
        s2 += v.x*v.x + v.y*v.y + v.z*v.z + v.w*v.w;
    }
    #pragma unroll
    for (int off = 1; off < 64; off <<= 1){
        s  += __shfl_xor(s,  off, 64);
        s2 += __shfl_xor(s2, off, 64);
    }
    const float mean = s * (1.0f/DIM);
    const float rstd = rsqrtf(s2*(1.0f/DIM) - mean*mean + 1e-5f);
    shortx4* MG = reinterpret_cast<shortx4*>(merged) + (size_t)row*256;
    #pragma unroll
    for (int j = 0; j < 4; ++j){
        f32x4 gg = reinterpret_cast<const f32x4*>(g1)[j*64 + lane];
        f32x4 bb = reinterpret_cast<const f32x4*>(bb1)[j*64 + lane];
        MG[j*64 + lane] = pack4((o[j] - mean)*rstd*gg + bb);
    }
}

// ---------------- K5: 256x256 bf16 GEMM — ring-10, lead-8, 1 barrier/phase ----
// Pieces of 16KB (A0,B0,B1,A1 per 64-K tile), slot = piece_idx % 10 (160KB LDS).
// Pair-iter = 2 K-tiles = 8 phases; phase = {ds_reads(12/4/8/0), stage piece
// P+8, [vmcnt@p3/p7 only], lgkm(0), setprio, 16 MFMA, setprio, s_barrier}.
// Safety: lgkm(0) precedes each wave's barrier; overwriting stage issues >=2
// barriers after last read of its slot; vmcnt(6)+barrier precedes first read
// of any staged piece (all waves). Tail: vmcnt(0) at last pair's p3.
typedef __attribute__((address_space(3))) unsigned int lds_uint;
typedef __attribute__((address_space(1))) unsigned int glob_uint;
static __device__ __forceinline__ void gload16(const unsigned short* g, char* l){
    __builtin_amdgcn_global_load_lds((const glob_uint*)g, (lds_uint*)l, 16, 0, 0);
}
#define SBAR() do { __builtin_amdgcn_sched_barrier(0); __builtin_amdgcn_s_barrier(); __builtin_amdgcn_sched_barrier(0); } while(0)
#define LGKM0() do { asm volatile("s_waitcnt lgkmcnt(0)" ::: "memory"); __builtin_amdgcn_sched_barrier(0); } while(0)
#define VMC(n)  asm volatile("s_waitcnt vmcnt(" #n ")" ::: "memory")
#define LDSE 136

__global__ __launch_bounds__(512, 2) void k_gemm(
    const unsigned short* __restrict__ A,    // merged bf16 [16384][1024]
    const unsigned short* __restrict__ Bt,   // Wcat  bf16 [2048][1024]
    const float* __restrict__ rbias, const float* __restrict__ vbias,
    unsigned short* __restrict__ gv)         // bf16 [16384][1024]
{
    __shared__ __align__(16) char lds[163840];   // 10 x 16KB ring
    const int tid  = threadIdx.x;
    const int lane = tid & 63;
    const int wid  = tid >> 6;
    const int wqm  = wid >> 2;       // 0..1
    const int wqn  = wid & 3;        // 0..3

    const int bid  = blockIdx.x;
    const int wgid = (bid & 7)*64 + (bid >> 3);
    const int mt = wgid >> 3, nt = wgid & 7;
    const int m0 = mt*256, n0 = nt*256;

    // staging source (pre-swizzled col-group)
    const int rin = lane >> 2;
    const int scg = (lane & 3) ^ (((lane >> 5) & 1) << 1);
    const unsigned short* gA = A  + (size_t)(m0 + wid*16 + rin)*DIM + scg*8;
    const unsigned short* gB = Bt + (size_t)(n0 + wid*16 + rin)*DIM + scg*8;

    // fragment read offset (matching swizzle)
    const int fr = lane & 15, fq = lane >> 4;
    const int soff = fr*64 + ((fq*16) ^ ((fr & 8) ? 32 : 0));

    f32x4 acc0[8], acc1[8], acc2[8], acc3[8];
    #pragma unroll
    for (int i = 0; i < 8; ++i){
        acc0[i] = (f32x4){0,0,0,0}; acc1[i] = (f32x4){0,0,0,0};
        acc2[i] = (f32x4){0,0,0,0}; acc3[i] = (f32x4){0,0,0,0};
    }

    // stage piece k (global idx; tile = k>>2, pc = k&3 in order A0,B0,B1,A1)
    auto STAGE_P = [&](int k){
        if (k >= 4*NTG) return;
        const int T = k >> 2, pc = k & 3, slot = k % 10;
        const int isA = (pc == 0 || pc == 3);
        const int h   = (pc >= 2) ? 1 : 0;
        char* dst = lds + slot*16384 + wid*2048;
        const unsigned short* s = (isA ? gA : gB) + (size_t)(h*128)*DIM + T*64;
        gload16(s,      dst);
        gload16(s + 32, dst + 1024);
    };

    shortx8 aA[8], bB0[4], bB1[4];
    auto LOAD_A = [&](int slot){
        const char* base = lds + slot*16384;
        #pragma unroll
        for (int rf = 0; rf < 4; ++rf)
            #pragma unroll
            for (int kb = 0; kb < 2; ++kb)
                aA[rf*2+kb] = *reinterpret_cast<const shortx8*>(
                    base + (wqm*4 + rf)*2048 + kb*1024 + soff);
    };
    auto LOAD_B = [&](int slot, shortx8* dst){
        const char* base = lds + slot*16384;
        #pragma unroll
        for (int cf = 0; cf < 2; ++cf)
            #pragma unroll
            for (int kb = 0; kb < 2; ++kb)
                dst[cf*2+kb] = *reinterpret_cast<const shortx8*>(
                    base + (wqn*2 + cf)*2048 + kb*1024 + soff);
    };

    #define MFMA16(ACC, BX)                                                     \
        __builtin_amdgcn_s_setprio(1);                                          \
        _Pragma("unroll")                                                       \
        for (int rf = 0; rf < 4; ++rf)                                          \
            _Pragma("unroll")                                                   \
            for (int cf = 0; cf < 2; ++cf){                                     \
                ACC[rf*2+cf] = __builtin_amdgcn_mfma_f32_16x16x32_bf16(         \
                    aA[rf*2+0], BX[cf*2+0], ACC[rf*2+cf], 0,0,0);               \
                ACC[rf*2+cf] = __builtin_amdgcn_mfma_f32_16x16x32_bf16(         \
                    aA[rf*2+1], BX[cf*2+1], ACC[rf*2+cf], 0,0,0);               \
            }                                                                   \
        __builtin_amdgcn_s_setprio(0);

    // prologue: pieces 0..7 (tiles 0,1); vmcnt(6) confirms pieces 0..4
    #pragma unroll
    for (int k = 0; k < 8; ++k) STAGE_P(k);
    VMC(6);
    SBAR();

    for (int i = 0; i < NPAIR; ++i){
        const int T0 = 2*i;
        const int sA0t0 = (4*T0  ) % 10, sB0t0 = (4*T0+1) % 10;
        const int sB1t0 = (4*T0+2) % 10, sA1t0 = (4*T0+3) % 10;
        const int sA0t1 = (4*T0+4) % 10, sB0t1 = (4*T0+5) % 10;
        const int sB1t1 = (4*T0+6) % 10, sA1t1 = (4*T0+7) % 10;
        const int P = 8*i;
        const bool last = (i == NPAIR-1);

        // p0: Q00(t0)
        LOAD_A(sA0t0); LOAD_B(sB0t0, bB0);
        STAGE_P(P + 8);
        LGKM0();
        MFMA16(acc0, bB0);
        SBAR();
        // p1: Q01(t0)
        LOAD_B(sB1t0, bB1);
        STAGE_P(P + 9);
        LGKM0();
        MFMA16(acc1, bB1);
        SBAR();
        // p2: Q11(t0)
        LOAD_A(sA1t0);
        STAGE_P(P + 10);
        LGKM0();
        MFMA16(acc3, bB1);
        SBAR();
        // p3: Q10(t0) — counted vmcnt
        STAGE_P(P + 11);
        if (last) { VMC(0); } else { VMC(6); }
        MFMA16(acc2, bB0);
        SBAR();
        // p4: Q00(t1)
        LOAD_A(sA0t1); LOAD_B(sB0t1, bB0);
        STAGE_P(P + 12);
        LGKM0();
        MFMA16(acc0, bB0);
        SBAR();
        // p5: Q01(t1)
        LOAD_B(sB1t1, bB1);
        STAGE_P(P + 13);
        LGKM0();
        MFMA16(acc1, bB1);
        SBAR();
        // p6: Q11(t1)
        LOAD_A(sA1t1);
        STAGE_P(P + 14);
        LGKM0();
        MFMA16(acc3, bB1);
        SBAR();
        // p7: Q10(t1) — counted vmcnt
        STAGE_P(P + 15);
        if (!last) { VMC(6); }
        MFMA16(acc2, bB0);
        SBAR();
    }

    // ---- epilogue: sigmoid(gate)*value -> padded LDS transpose -> store ----
    __syncthreads();
    unsigned short* ep = reinterpret_cast<unsigned short*>(lds);  // [256][LDSE]
    #pragma unroll
    for (int q = 0; q < 4; ++q){
        const f32x4* ac = (q==0) ? acc0 : (q==1) ? acc1 : (q==2) ? acc2 : acc3;
        const int QM = q >> 1, QN = q & 1;
        const int el = QN*64 + wqn*16 + fr;            // 0..127
        const float rbe = rbias[nt*128 + el];
        const float vbe = vbias[nt*128 + el];
        #pragma unroll
        for (int rf = 0; rf < 4; ++rf){
            const int rbase = QM*128 + wqm*64 + rf*16 + fq*4;
            f32x4 ga = ac[rf*2+0], va = ac[rf*2+1];
            #pragma unroll
            for (int qq = 0; qq < 4; ++qq){
                const float g = sigmoidf_fast(ga[qq] + rbe);
                ep[(rbase + qq)*LDSE + el] = f2bf(g*(va[qq] + vbe));
            }
        }
    }
    __syncthreads();
    #pragma unroll
    for (int p = 0; p < 8; ++p){
        const int r  = p*32 + (tid >> 4);
        const int c8 = tid & 15;
        shortx8 val = *reinterpret_cast<const shortx8*>(&ep[r*LDSE + c8*8]);
        *reinterpret_cast<shortx8*>(&gv[(size_t)(m0 + r)*DIM + nt*128 + c8*8]) = val;
    }
    #undef MFMA16
}

// ---------------- K6: LN2 + residual (wave-per-row) ----------------
__global__ __launch_bounds__(256) void k_ln2_res(
    const unsigned short* __restrict__ gvb, const unsigned short* __restrict__ shifted,
    const float* __restrict__ g2, const float* __restrict__ b2,
    float* __restrict__ out)
{
    const int tid = threadIdx.x, lane = tid & 63, wid = tid >> 6;
    const int row = blockIdx.x*4 + wid;

    const shortx4* GV = reinterpret_cast<const shortx4*>(gvb) + (size_t)row*256;
    const shortx4* SH = reinterpret_cast<const shortx4*>(shifted) + (size_t)row*256;

    f32x4 v[4];
    float s = 0.f, s2 = 0.f;
    #pragma unroll
    for (int j = 0; j < 4; ++j){
        f32x4 x = unpack4(GV[j*64 + lane]);
        v[j] = x;
        s  += x.x+x.y+x.z+x.w;
        s2 += x.x*x.x + x.y*x.y + x.z*x.z + x.w*x.w;
    }
    #pragma unroll
    for (int off = 1; off < 64; off <<= 1){
        s  += __shfl_xor(s,  off, 64);
        s2 += __shfl_xor(s2, off, 64);
    }
    const float mean = s * (1.0f/DIM);
    const float rstd = rsqrtf(s2*(1.0f/DIM) - mean*mean + 1e-5f);
    f32x4* O = reinterpret_cast<f32x4*>(out) + (size_t)row*256;
    #pragma unroll
    for (int j = 0; j < 4; ++j){
        f32x4 gg = reinterpret_cast<const f32x4*>(g2)[j*64 + lane];
        f32x4 bb = reinterpret_cast<const f32x4*>(b2)[j*64 + lane];
        f32x4 sh = unpack4(SH[j*64 + lane]);
        O[j*64 + lane] = sh + (v[j] - mean)*rstd*gg + bb;
    }
}

extern "C" void kernel_launch(void* const* d_in, const int* in_sizes, int n_in,
                              void* d_out, int out_size, void* d_ws, size_t ws_size,
                              hipStream_t stream)
{
    (void)in_sizes; (void)n_in; (void)out_size; (void)ws_size;
    const float* x     = (const float*)d_in[0];
    const float* xprev = (const float*)d_in[1];
    const float* mu    = (const float*)d_in[2];
    const float* dw    = (const float*)d_in[3];
    const float* db    = (const float*)d_in[4];
    const float* ln1g  = (const float*)d_in[5];
    const float* ln1b  = (const float*)d_in[6];
    const float* Wr    = (const float*)d_in[7];
    const float* Wrb   = (const float*)d_in[8];
    const float* Wv    = (const float*)d_in[9];
    const float* Wvb   = (const float*)d_in[10];
    const float* ln2g  = (const float*)d_in[11];
    const float* ln2b  = (const float*)d_in[12];
    float* out = (float*)d_out;

    char* ws = (char*)d_ws;
    size_t off = 0;
    auto alloc = [&](size_t bytes) -> void* {
        void* p = ws + off;
        off += (bytes + 255) & ~(size_t)255;
        return p;
    };
    unsigned short* shifted = (unsigned short*)alloc((size_t)NROWS*DIM*2);
    unsigned short* b_local = (unsigned short*)alloc((size_t)NROWS*DIM*2);
    unsigned short* merged  = (unsigned short*)alloc((size_t)NROWS*DIM*2);
    unsigned short* carryB  = (unsigned short*)alloc((size_t)BATCH*NCH*DIM*2);
    unsigned short* Wcat    = (unsigned short*)alloc((size_t)2048*1024*2);
    float* a_local          = (float*)alloc((size_t)NROWS*4);
    float* cumP             = (float*)alloc((size_t)NROWS*4);
    float* carryA           = (float*)alloc((size_t)BATCH*NCH*4);
    unsigned short* gvbuf   = b_local;   // b_local dead after k_fix_ln1

    hipLaunchKernelGGL(k_shift_scan, dim3(576),  dim3(256), 0, stream,
                       x, xprev, mu, dw, db, Wr, Wv, Wcat, shifted, b_local, a_local, cumP);
    hipLaunchKernelGGL(k_combine,    dim3(16),   dim3(64),  0, stream,
                       b_local, a_local, cumP, carryA, carryB);
    hipLaunchKernelGGL(k_fix_ln1,    dim3(4096), dim3(256), 0, stream,
                       b_local, a_local, cumP, carryA, carryB, ln1g, ln1b, merged);
    hipLaunchKernelGGL(k_gemm,       dim3(512),  dim3(512), 0, stream,
                       merged, Wcat, Wrb, Wvb, gvbuf);
    hipLaunchKernelGGL(k_ln2_res,    dim3(4096), dim3(256), 0, stream,
                       gvbuf, shifted, ln2g, ln2b, out);
}

// Round 9
// 205.032 us; speedup vs baseline: 1.0273x; 1.0150x over previous
//
#include <hip/hip_runtime.h>

#define BATCH 4
#define SEQ   4096
#define DIM   1024
#define NCH   512
#define CHK   8
#define NROWS (BATCH*SEQ)
#define NTG   16            // gemm K-tiles (1024/64)

typedef __attribute__((ext_vector_type(4))) float f32x4;
typedef __attribute__((ext_vector_type(8))) short shortx8;
typedef __attribute__((ext_vector_type(4))) short shortx4;

static __device__ __forceinline__ unsigned short f2bf(float f){
    unsigned int u = __float_as_uint(f);
    u += 0x7FFFu + ((u >> 16) & 1u);
    return (unsigned short)(u >> 16);
}
static __device__ __forceinline__ float bf2f(unsigned short h){
    return __uint_as_float(((unsigned int)h) << 16);
}
static __device__ __forceinline__ float sigmoidf_fast(float x){
    return 1.0f / (1.0f + __expf(-x));
}
static __device__ __forceinline__ shortx4 pack4(f32x4 s){
    shortx4 o;
    o.x = (short)f2bf(s.x); o.y = (short)f2bf(s.y);
    o.z = (short)f2bf(s.z); o.w = (short)f2bf(s.w);
    return o;
}
static __device__ __forceinline__ f32x4 unpack4(shortx4 s){
    f32x4 o;
    o.x = bf2f((unsigned short)s.x); o.y = bf2f((unsigned short)s.y);
    o.z = bf2f((unsigned short)s.z); o.w = bf2f((unsigned short)s.w);
    return o;
}

// ---------------- K1: shift + decay + exp + chunk-local scan (+ fused W-pack) ----
__global__ __launch_bounds__(256) void k_shift_scan(
    const float* __restrict__ X, const float* __restrict__ XP,
    const float* __restrict__ mu_p, const float* __restrict__ dw,
    const float* __restrict__ db_p,
    const float* __restrict__ Wr, const float* __restrict__ Wv,
    unsigned short* __restrict__ Wcat,
    unsigned short* __restrict__ shifted,
    unsigned short* __restrict__ b_local, float* __restrict__ a_local,
    float* __restrict__ cumP)
{
    const int tid  = threadIdx.x;

    if (blockIdx.x >= 512){            // ---- weight pack path ----
        const int pb = blockIdx.x - 512;       // 0..63
        #pragma unroll 4
        for (int i = 0; i < 32; ++i){
            const int n = pb*32 + i;
            const int grp = n >> 5, r = n & 31;
            const float* src = (r < 16) ? (Wr + (size_t)(grp*16 + r)*DIM)
                                        : (Wv + (size_t)(grp*16 + (r-16))*DIM);
            f32x4 v = reinterpret_cast<const f32x4*>(src)[tid];
            reinterpret_cast<shortx4*>(Wcat)[n*256 + tid] = pack4(v);
        }
        return;
    }

    const int lane = tid & 63;
    const int wid  = tid >> 6;
    const int cid  = blockIdx.x*4 + wid;
    const int batch = cid >> 9;
    const int chunk = cid & (NCH-1);
    const int row0  = batch*SEQ + chunk*CHK;

    const float mu = mu_p[0];
    const float om = 1.0f - mu;
    const float db = db_p[0];

    const f32x4* dwv = reinterpret_cast<const f32x4*>(dw);
    const f32x4 w0 = dwv[lane], w1 = dwv[64+lane], w2 = dwv[128+lane], w3 = dwv[192+lane];

    f32x4 b0 = {0,0,0,0}, b1 = {0,0,0,0}, b2 = {0,0,0,0}, b3 = {0,0,0,0};
    float a_run = 0.f, cp = 1.f;

    const f32x4* Xv  = reinterpret_cast<const f32x4*>(X);
    const f32x4* XPv = reinterpret_cast<const f32x4*>(XP);
    shortx4* BL = reinterpret_cast<shortx4*>(b_local);
    shortx4* SH = reinterpret_cast<shortx4*>(shifted);

    for (int r = 0; r < CHK; ++r){
        const int row = row0 + r;
        const int rb  = row*(DIM/4);

        f32x4 x0 = Xv[rb+lane],     x1 = Xv[rb+64+lane],
              x2 = Xv[rb+128+lane], x3 = Xv[rb+192+lane];
        f32x4 p0 = XPv[rb+lane],     p1 = XPv[rb+64+lane],
              p2 = XPv[rb+128+lane], p3 = XPv[rb+192+lane];
        f32x4 s0 = mu*x0 + om*p0, s1 = mu*x1 + om*p1;
        f32x4 s2 = mu*x2 + om*p2, s3 = mu*x3 + om*p3;

        SH[rb+lane]     = pack4(s0);
        SH[rb+64+lane]  = pack4(s1);
        SH[rb+128+lane] = pack4(s2);
        SH[rb+192+lane] = pack4(s3);

        float dot = s0.x*w0.x + s0.y*w0.y + s0.z*w0.z + s0.w*w0.w
                  + s1.x*w1.x + s1.y*w1.y + s1.z*w1.z + s1.w*w1.w
                  + s2.x*w2.x + s2.y*w2.y + s2.z*w2.z + s2.w*w2.w
                  + s3.x*w3.x + s3.y*w3.y + s3.z*w3.z + s3.w*w3.w;

        f32x4 e0, e1, e2, e3;
        e0.x=__expf(s0.x); e0.y=__expf(s0.y); e0.z=__expf(s0.z); e0.w=__expf(s0.w);
        e1.x=__expf(s1.x); e1.y=__expf(s1.y); e1.z=__expf(s1.z); e1.w=__expf(s1.w);
        e2.x=__expf(s2.x); e2.y=__expf(s2.y); e2.z=__expf(s2.z); e2.w=__expf(s2.w);
        e3.x=__expf(s3.x); e3.y=__expf(s3.y); e3.z=__expf(s3.z); e3.w=__expf(s3.w);
        float ea = e0.x+e0.y+e0.z+e0.w + e1.x+e1.y+e1.z+e1.w
                 + e2.x+e2.y+e2.z+e2.w + e3.x+e3.y+e3.z+e3.w;

        #pragma unroll
        for (int off = 1; off < 64; off <<= 1){
            dot += __shfl_xor(dot, off, 64);
            ea  += __shfl_xor(ea,  off, 64);
        }

        const float dt = sigmoidf_fast(dot + db);
        a_run = dt*a_run + ea;
        cp   *= dt;
        b0 = dt*b0 + e0*s0;  b1 = dt*b1 + e1*s1;
        b2 = dt*b2 + e2*s2;  b3 = dt*b3 + e3*s3;

        BL[rb+lane]     = pack4(b0);
        BL[rb+64+lane]  = pack4(b1);
        BL[rb+128+lane] = pack4(b2);
        BL[rb+192+lane] = pack4(b3);
        if (lane == 0){ a_local[row] = a_run; cumP[row] = cp; }
    }
}

// ---------------- K2: sequential carry combine (depth-16 vector prefetch) ----
__global__ __launch_bounds__(64) void k_combine(
    const unsigned short* __restrict__ b_local, const float* __restrict__ a_local,
    const float* __restrict__ cumP,
    float* __restrict__ carryA, unsigned short* __restrict__ carryB)
{
    const int batch = blockIdx.x >> 2;
    const int dseg  = blockIdx.x & 3;
    const int tid = threadIdx.x;
    const int d0 = dseg*256 + tid*4;

    __shared__ float sP[NCH], sA[NCH];
    for (int c = tid; c < NCH; c += 64){
        const int er = batch*SEQ + c*CHK + (CHK-1);
        sP[c] = cumP[er];
        sA[c] = a_local[er];
    }
    __syncthreads();

    const unsigned short* bl = b_local + (size_t)batch*SEQ*DIM + d0;
    unsigned short* cB = carryB + (size_t)batch*NCH*DIM + d0;
    const bool wA = (dseg == 0 && tid == 0);
    float* cAp = carryA + batch*NCH;

    shortx4 pf[16];
    #pragma unroll
    for (int i = 0; i < 16; ++i)
        pf[i] = *reinterpret_cast<const shortx4*>(bl + (i*CHK + CHK-1)*DIM);

    f32x4 cb = {0,0,0,0};
    float ca = 0.f;

    for (int cc = 0; cc < NCH; cc += 16){
        const bool more = (cc + 16 < NCH);
        #pragma unroll
        for (int k = 0; k < 16; ++k){
            const int c = cc + k;
            f32x4 v = unpack4(pf[k]);
            if (more)
                pf[k] = *reinterpret_cast<const shortx4*>(bl + ((c+16)*CHK + CHK-1)*DIM);
            *reinterpret_cast<shortx4*>(cB + (size_t)c*DIM) = pack4(cb);
            if (wA) cAp[c] = ca;
            const float p = sP[c];
            cb = p*cb + v;
            ca = p*ca + sA[c];
        }
    }
}

// ---------------- K3: carry fixup + divide + LN1 -> merged (wave-per-row) ----
__global__ __launch_bounds__(256) void k_fix_ln1(
    const unsigned short* __restrict__ b_local, const float* __restrict__ a_local,
    const float* __restrict__ cumP, const float* __restrict__ carryA,
    const unsigned short* __restrict__ carryB,
    const float* __restrict__ g1, const float* __restrict__ bb1,
    unsigned short* __restrict__ merged)
{
    const int tid = threadIdx.x, lane = tid & 63, wid = tid >> 6;
    const int row = blockIdx.x*4 + wid;
    const int batch = row >> 12;
    const int c = (row & (SEQ-1)) >> 3;

    const float cpv = cumP[row];
    const float a = a_local[row] + cpv * carryA[batch*NCH + c];
    const float inv_a = 1.0f / (a + 1e-8f);

    const shortx4* BL = reinterpret_cast<const shortx4*>(b_local) + (size_t)row*256;
    const shortx4* CB = reinterpret_cast<const shortx4*>(carryB) + (size_t)(batch*NCH + c)*256;

    f32x4 o[4];
    float s = 0.f, s2 = 0.f;
    #pragma unroll
    for (int j = 0; j < 4; ++j){
        f32x4 bl = unpack4(BL[j*64 + lane]);
        f32x4 cb = unpack4(CB[j*64 + lane]);
        f32x4 v = (bl + cpv*cb) * inv_a;
        o[j] = v;
        s  += v.x+v.y+v.z+v.w;
        s2 += v.x*v.x + v.y*v.y + v.z*v.z + v.w*v.w;
    }
    #pragma unroll
    for (int off = 1; off < 64; off <<= 1){
        s  += __shfl_xor(s,  off, 64);
        s2 += __shfl_xor(s2, off, 64);
    }
    const float mean = s * (1.0f/DIM);
    const float rstd = rsqrtf(s2*(1.0f/DIM) - mean*mean + 1e-5f);
    shortx4* MG = reinterpret_cast<shortx4*>(merged) + (size_t)row*256;
    #pragma unroll
    for (int j = 0; j < 4; ++j){
        f32x4 gg = reinterpret_cast<const f32x4*>(g1)[j*64 + lane];
        f32x4 bb = reinterpret_cast<const f32x4*>(bb1)[j*64 + lane];
        MG[j*64 + lane] = pack4((o[j] - mean)*rstd*gg + bb);
    }
}

// ---------------- K5: 256x256 bf16 GEMM — ring-10, ONE barrier per K-tile ----
// Pieces 16KB (A0,B0,B1,A1 per BK=64 tile), slot = piece % 10 (160KB LDS).
// Per tile T: read window {4T..4T+3}, stage window {4T+6..4T+9} — disjoint
// mod 10; every stage overwrites a slot last read in tile T-1 (drained by
// that wave's lgkm(0) before barrier(T-1)) -> all stages safe at tile top.
// VMC(4) at tile end (issue order [6,7,8,9]) confirms pieces <=4T+7 = all of
// tile T+1's reads before barrier(T). VMC(0) at T=NTG-2 covers the tail.
// Intra-tile: NO barriers — per-wave lgkm waits only; waves skew a full tile
// so one wave's MFMA covers another's ds_reads (LDS/matrix pipe overlap).
typedef __attribute__((address_space(3))) unsigned int lds_uint;
typedef __attribute__((address_space(1))) unsigned int glob_uint;
static __device__ __forceinline__ void gload16(const unsigned short* g, char* l){
    __builtin_amdgcn_global_load_lds((const glob_uint*)g, (lds_uint*)l, 16, 0, 0);
}
#define SBAR() do { __builtin_amdgcn_sched_barrier(0); __builtin_amdgcn_s_barrier(); __builtin_amdgcn_sched_barrier(0); } while(0)
#define LGKM(n) do { asm volatile("s_waitcnt lgkmcnt(" #n ")" ::: "memory"); __builtin_amdgcn_sched_barrier(0); } while(0)
#define VMC(n)  do { asm volatile("s_waitcnt vmcnt(" #n ")" ::: "memory"); __builtin_amdgcn_sched_barrier(0); } while(0)
#define LDSE 136

__global__ __launch_bounds__(512, 2) void k_gemm(
    const unsigned short* __restrict__ A,    // merged bf16 [16384][1024]
    const unsigned short* __restrict__ Bt,   // Wcat  bf16 [2048][1024]
    const float* __restrict__ rbias, const float* __restrict__ vbias,
    unsigned short* __restrict__ gv)         // bf16 [16384][1024]
{
    __shared__ __align__(16) char lds[163840];   // 10 x 16KB ring
    const int tid  = threadIdx.x;
    const int lane = tid & 63;
    const int wid  = tid >> 6;
    const int wqm  = wid >> 2;       // 0..1
    const int wqn  = wid & 3;        // 0..3

    const int bid  = blockIdx.x;
    const int wgid = (bid & 7)*64 + (bid >> 3);
    const int mt = wgid >> 3, nt = wgid & 7;
    const int m0 = mt*256, n0 = nt*256;

    // staging source (pre-swizzled col-group)
    const int rin = lane >> 2;
    const int scg = (lane & 3) ^ (((lane >> 5) & 1) << 1);
    const unsigned short* gA = A  + (size_t)(m0 + wid*16 + rin)*DIM + scg*8;
    const unsigned short* gB = Bt + (size_t)(n0 + wid*16 + rin)*DIM + scg*8;

    // fragment read offset (matching swizzle)
    const int fr = lane & 15, fq = lane >> 4;
    const int soff = fr*64 + ((fq*16) ^ ((fr & 8) ? 32 : 0));

    f32x4 acc0[8], acc1[8], acc2[8], acc3[8];
    #pragma unroll
    for (int i = 0; i < 8; ++i){
        acc0[i] = (f32x4){0,0,0,0}; acc1[i] = (f32x4){0,0,0,0};
        acc2[i] = (f32x4){0,0,0,0}; acc3[i] = (f32x4){0,0,0,0};
    }

    // stage piece k (tile = k>>2, pc = k&3 in order A0,B0,B1,A1)
    auto STAGE_P = [&](int k){
        if (k >= 4*NTG) return;
        const int T = k >> 2, pc = k & 3, slot = k % 10;
        const int isA = (pc == 0 || pc == 3);
        const int h   = (pc >= 2) ? 1 : 0;
        char* dst = lds + slot*16384 + wid*2048;
        const unsigned short* s = (isA ? gA : gB) + (size_t)(h*128)*DIM + T*64;
        gload16(s,      dst);
        gload16(s + 32, dst + 1024);
    };

    shortx8 aA[8], bB0[4], bB1[4];
    auto LOAD_A = [&](int slot){
        const char* base = lds + slot*16384;
        #pragma unroll
        for (int rf = 0; rf < 4; ++rf)
            #pragma unroll
            for (int kb = 0; kb < 2; ++kb)
                aA[rf*2+kb] = *reinterpret_cast<const shortx8*>(
                    base + (wqm*4 + rf)*2048 + kb*1024 + soff);
    };
    auto LOAD_B = [&](int slot, shortx8* dst){
        const char* base = lds + slot*16384;
        #pragma unroll
        for (int cf = 0; cf < 2; ++cf)
            #pragma unroll
            for (int kb = 0; kb < 2; ++kb)
                dst[cf*2+kb] = *reinterpret_cast<const shortx8*>(
                    base + (wqn*2 + cf)*2048 + kb*1024 + soff);
    };

    #define MFMA16(ACC, BX)                                                     \
        __builtin_amdgcn_s_setprio(1);                                          \
        _Pragma("unroll")                                                       \
        for (int rf = 0; rf < 4; ++rf)                                          \
            _Pragma("unroll")                                                   \
            for (int cf = 0; cf < 2; ++cf){                                     \
                ACC[rf*2+cf] = __builtin_amdgcn_mfma_f32_16x16x32_bf16(         \
                    aA[rf*2+0], BX[cf*2+0], ACC[rf*2+cf], 0,0,0);               \
                ACC[rf*2+cf] = __builtin_amdgcn_mfma_f32_16x16x32_bf16(         \
                    aA[rf*2+1], BX[cf*2+1], ACC[rf*2+cf], 0,0,0);               \
            }                                                                   \
        __builtin_amdgcn_s_setprio(0);

    // prologue: pieces 0..5 (tile0 + tile1's A0,B0); VMC(4) confirms tile 0
    #pragma unroll
    for (int k = 0; k < 6; ++k) STAGE_P(k);
    VMC(4);
    SBAR();

    #pragma unroll
    for (int T = 0; T < NTG; ++T){
        const int p0 = 4*T;
        // stage window {4T+6..4T+9}: all overwrite tile-(T-1) slots -> safe
        STAGE_P(p0+6); STAGE_P(p0+7); STAGE_P(p0+8); STAGE_P(p0+9);

        const int sA0 = p0 % 10, sB0 = (p0+1) % 10;
        const int sB1 = (p0+2) % 10, sA1 = (p0+3) % 10;

        LOAD_A(sA0);             // 8 ds_reads
        LOAD_B(sB0, bB0);        // 4
        LOAD_B(sB1, bB1);        // 4
        LGKM(4);                 // A0,B0 landed (B1 may be in flight)
        MFMA16(acc0, bB0);       // Q00
        LGKM(0);                 // B1 landed
        MFMA16(acc1, bB1);       // Q01
        LOAD_A(sA1);             // 8 ds_reads
        LGKM(0);                 // A1 landed
        MFMA16(acc3, bB1);       // Q11
        MFMA16(acc2, bB0);       // Q10

        if (T < NTG-2)       { VMC(4); }   // confirms pieces <= 4T+7
        else if (T == NTG-2) { VMC(0); }   // tail drain
        SBAR();                  // the ONLY barrier per tile
    }

    // ---- epilogue: sigmoid(gate)*value -> padded LDS transpose -> store ----
    __syncthreads();
    unsigned short* ep = reinterpret_cast<unsigned short*>(lds);  // [256][LDSE]
    #pragma unroll
    for (int q = 0; q < 4; ++q){
        const f32x4* ac = (q==0) ? acc0 : (q==1) ? acc1 : (q==2) ? acc2 : acc3;
        const int QM = q >> 1, QN = q & 1;
        const int el = QN*64 + wqn*16 + fr;            // 0..127
        const float rbe = rbias[nt*128 + el];
        const float vbe = vbias[nt*128 + el];
        #pragma unroll
        for (int rf = 0; rf < 4; ++rf){
            const int rbase = QM*128 + wqm*64 + rf*16 + fq*4;
            f32x4 ga = ac[rf*2+0], va = ac[rf*2+1];
            #pragma unroll
            for (int qq = 0; qq < 4; ++qq){
                const float g = sigmoidf_fast(ga[qq] + rbe);
                ep[(rbase + qq)*LDSE + el] = f2bf(g*(va[qq] + vbe));
            }
        }
    }
    __syncthreads();
    #pragma unroll
    for (int p = 0; p < 8; ++p){
        const int r  = p*32 + (tid >> 4);
        const int c8 = tid & 15;
        shortx8 val = *reinterpret_cast<const shortx8*>(&ep[r*LDSE + c8*8]);
        *reinterpret_cast<shortx8*>(&gv[(size_t)(m0 + r)*DIM + nt*128 + c8*8]) = val;
    }
    #undef MFMA16
}

// ---------------- K6: LN2 + residual (wave-per-row) ----------------
__global__ __launch_bounds__(256) void k_ln2_res(
    const unsigned short* __restrict__ gvb, const unsigned short* __restrict__ shifted,
    const float* __restrict__ g2, const float* __restrict__ b2,
    float* __restrict__ out)
{
    const int tid = threadIdx.x, lane = tid & 63, wid = tid >> 6;
    const int row = blockIdx.x*4 + wid;

    const shortx4* GV = reinterpret_cast<const shortx4*>(gvb) + (size_t)row*256;
    const shortx4* SH = reinterpret_cast<const shortx4*>(shifted) + (size_t)row*256;

    f32x4 v[4];
    float s = 0.f, s2 = 0.f;
    #pragma unroll
    for (int j = 0; j < 4; ++j){
        f32x4 x = unpack4(GV[j*64 + lane]);
        v[j] = x;
        s  += x.x+x.y+x.z+x.w;
        s2 += x.x*x.x + x.y*x.y + x.z*x.z + x.w*x.w;
    }
    #pragma unroll
    for (int off = 1; off < 64; off <<= 1){
        s  += __shfl_xor(s,  off, 64);
        s2 += __shfl_xor(s2, off, 64);
    }
    const float mean = s * (1.0f/DIM);
    const float rstd = rsqrtf(s2*(1.0f/DIM) - mean*mean + 1e-5f);
    f32x4* O = reinterpret_cast<f32x4*>(out) + (size_t)row*256;
    #pragma unroll
    for (int j = 0; j < 4; ++j){
        f32x4 gg = reinterpret_cast<const f32x4*>(g2)[j*64 + lane];
        f32x4 bb = reinterpret_cast<const f32x4*>(b2)[j*64 + lane];
        f32x4 sh = unpack4(SH[j*64 + lane]);
        O[j*64 + lane] = sh + (v[j] - mean)*rstd*gg + bb;
    }
}

extern "C" void kernel_launch(void* const* d_in, const int* in_sizes, int n_in,
                              void* d_out, int out_size, void* d_ws, size_t ws_size,
                              hipStream_t stream)
{
    (void)in_sizes; (void)n_in; (void)out_size; (void)ws_size;
    const float* x     = (const float*)d_in[0];
    const float* xprev = (const float*)d_in[1];
    const float* mu    = (const float*)d_in[2];
    const float* dw    = (const float*)d_in[3];
    const float* db    = (const float*)d_in[4];
    const float* ln1g  = (const float*)d_in[5];
    const float* ln1b  = (const float*)d_in[6];
    const float* Wr    = (const float*)d_in[7];
    const float* Wrb   = (const float*)d_in[8];
    const float* Wv    = (const float*)d_in[9];
    const float* Wvb   = (const float*)d_in[10];
    const float* ln2g  = (const float*)d_in[11];
    const float* ln2b  = (const float*)d_in[12];
    float* out = (float*)d_out;

    char* ws = (char*)d_ws;
    size_t off = 0;
    auto alloc = [&](size_t bytes) -> void* {
        void* p = ws + off;
        off += (bytes + 255) & ~(size_t)255;
        return p;
    };
    unsigned short* shifted = (unsigned short*)alloc((size_t)NROWS*DIM*2);
    unsigned short* b_local = (unsigned short*)alloc((size_t)NROWS*DIM*2);
    unsigned short* merged  = (unsigned short*)alloc((size_t)NROWS*DIM*2);
    unsigned short* carryB  = (unsigned short*)alloc((size_t)BATCH*NCH*DIM*2);
    unsigned short* Wcat    = (unsigned short*)alloc((size_t)2048*1024*2);
    float* a_local          = (float*)alloc((size_t)NROWS*4);
    float* cumP             = (float*)alloc((size_t)NROWS*4);
    float* carryA           = (float*)alloc((size_t)BATCH*NCH*4);
    unsigned short* gvbuf   = b_local;   // b_local dead after k_fix_ln1

    hipLaunchKernelGGL(k_shift_scan, dim3(576),  dim3(256), 0, stream,
                       x, xprev, mu, dw, db, Wr, Wv, Wcat, shifted, b_local, a_local, cumP);
    hipLaunchKernelGGL(k_combine,    dim3(16),   dim3(64),  0, stream,
                       b_local, a_local, cumP, carryA, carryB);
    hipLaunchKernelGGL(k_fix_ln1,    dim3(4096), dim3(256), 0, stream,
                       b_local, a_local, cumP, carryA, carryB, ln1g, ln1b, merged);
    hipLaunchKernelGGL(k_gemm,       dim3(512),  dim3(512), 0, stream,
                       merged, Wcat, Wrb, Wvb, gvbuf);
    hipLaunchKernelGGL(k_ln2_res,    dim3(4096), dim3(256), 0, stream,
                       gvbuf, shifted, ln2g, ln2b, out);
}